// Round 1
// 191.680 us; speedup vs baseline: 1.1116x; 1.1116x over previous
//
#include <hip/hip_runtime.h>
#include <hip/hip_bf16.h>

typedef __attribute__((ext_vector_type(8))) short short8;
typedef __attribute__((ext_vector_type(4))) float floatx4;

#define B_SZ   32
#define L_IN   8192
#define C_INCH 64
#define KW     3
#define F_OUT  128
#define L_OUT  (L_IN - KW + 1)   // 8190
#define KDIM   (KW * C_INCH)     // 192

#define TILE_L  64
#define AROWS   (TILE_L + 2)     // 66
#define ASTRIDE 72               // 64 + 8 pad
#define NGRID   (B_SZ * (L_IN / TILE_L))   // 4096 blocks, TPB=1

// W fragment table: 8 n-tiles x 6 k-steps x 64 lanes, one short8 (16B) each.
#define WTAB_ELEMS (8 * 6 * 64)            // 3072 -> 49152 bytes

// packed fp32x2 -> bf16x2 (RNE, emits v_cvt_pk_bf16_f32)
__device__ __forceinline__ unsigned pk2(float a, float b) {
    __hip_bfloat162 h = __float22bfloat162_rn(make_float2(a, b));
    unsigned u;
    __builtin_memcpy(&u, &h, 4);
    return u;
}

// R7 prep: pre-swizzle w (fp32 [192][128]) into bf16 MFMA fragment layout.
// wtab[(nt*6 + s)*64 + lane] holds W[k = s*32 + q*8 + j][f = nt*16 + nl],
// j=0..7 packed as bf16 pairs. Main kernel then loads bfrag with 12
// lane-coalesced dwordx4 L2 hits instead of 96 strided scalar loads + 48 cvt.
__global__ __launch_bounds__(256) void w_prep(const float* __restrict__ w,
                                              short8* __restrict__ wtab) {
    int id = blockIdx.x * 256 + threadIdx.x;
    if (id >= WTAB_ELEMS) return;
    int lane = id & 63;
    int s    = (id >> 6) % 6;
    int nt   = id / 384;
    int nl = lane & 15, q = lane >> 4;
    const float* __restrict__ wf = w + nt * 16 + nl;
    float t[8];
#pragma unroll
    for (int j = 0; j < 8; ++j) t[j] = wf[(s * 32 + q * 8 + j) * F_OUT];
    union { unsigned u[4]; short8 v; } hb;
    hb.u[0] = pk2(t[0], t[1]);
    hb.u[1] = pk2(t[2], t[3]);
    hb.u[2] = pk2(t[4], t[5]);
    hb.u[3] = pk2(t[6], t[7]);
    wtab[id] = hb.v;
}

// R7 main: implicit GEMM, one 64-row L-tile per block (grid 4096, was 1024).
// SWAPPED operands: mfma(bfrag, af, acc) computes (X*W)^T. A-frag and B-frag
// of 16x16x32_bf16 share the same lane->(non-K idx = nl, K idx = q*8+j)
// mapping, so the same register data serves either role; only C/D flips:
// lane(nl,q) reg r now holds D[f = ntile*16 + q*4 + r][l = m*16 + nl]
// -> 4 consecutive f per lane -> float4 epilogue stores (8 dwordx4/thread,
// was 32 dword). launch_bounds (256,4): live set is bfrag 48 VGPR + ~20 temps
// + 32 AGPR acc <= 128 unified budget (R5's spill had +24 xv prefetch regs
// and the in-kernel w-build; both gone now).
template <bool PREP>
__global__ __launch_bounds__(256, 4) void conv1d_mfma(const float* __restrict__ x,
                                                      const float* __restrict__ w,
                                                      const float* __restrict__ bias,
                                                      float* __restrict__ out,
                                                      const short8* __restrict__ wtab) {
    __shared__ short a_lds[AROWS * ASTRIDE];  // 9504 B, single buffer

    const int tid  = threadIdx.x;
    const int lane = tid & 63;
    const int wave = tid >> 6;
    const int q    = lane >> 4;   // quad 0..3
    const int nl   = lane & 15;

    const int g  = blockIdx.x;
    const int b  = g >> 7;              // L_IN/TILE_L = 128 tiles per batch row
    const int l0 = (g & 127) * TILE_L;

    // ---- B fragments: 12 coalesced 16B loads from the prepped table ----
    short8 bfrag[6][2];
    if (PREP) {
#pragma unroll
        for (int n = 0; n < 2; ++n)
#pragma unroll
            for (int s = 0; s < 6; ++s)
                bfrag[s][n] = wtab[(((wave * 2 + n) * 6 + s) << 6) + lane];
    } else {
        // fallback (workspace too small): build in-kernel as before
#pragma unroll
        for (int n = 0; n < 2; ++n) {
            const int f = (wave * 2 + n) * 16 + nl;
            const float* __restrict__ wf = w + f;
#pragma unroll
            for (int s = 0; s < 6; ++s) {
                float t[8];
#pragma unroll
                for (int j = 0; j < 8; ++j)
                    t[j] = wf[(s * 32 + q * 8 + j) * F_OUT];
                union { unsigned u[4]; short8 v; } hb;
                hb.u[0] = pk2(t[0], t[1]);
                hb.u[1] = pk2(t[2], t[3]);
                hb.u[2] = pk2(t[4], t[5]);
                hb.u[3] = pk2(t[6], t[7]);
                bfrag[s][n] = hb.v;
            }
        }
    }

    // bias: with swapped C/D layout, lane holds f = base + q*4 + r -> float4
    float4 bv[2];
#pragma unroll
    for (int n = 0; n < 2; ++n)
        bv[n] = *(const float4*)(bias + (wave * 2 + n) * 16 + q * 4);

    // ---- stage x tile: fp32 -> bf16 into LDS ----
#pragma unroll
    for (int i = 0; i < 3; ++i) {
        int c = tid + 256 * i;
        if (c < AROWS * 8) {
            int p   = c >> 3;
            int col = (c & 7) * 8;
            int gl  = l0 + p;
            float4 v0, v1;
            if (gl < L_IN) {
                const float4* xp =
                    (const float4*)(x + ((size_t)b * L_IN + gl) * C_INCH + col);
                v0 = xp[0];
                v1 = xp[1];
            } else {
                v0 = make_float4(0.f, 0.f, 0.f, 0.f);
                v1 = v0;
            }
            union { unsigned u[4]; short8 v; } h;
            h.u[0] = pk2(v0.x, v0.y);
            h.u[1] = pk2(v0.z, v0.w);
            h.u[2] = pk2(v1.x, v1.y);
            h.u[3] = pk2(v1.z, v1.w);
            *(short8*)&a_lds[p * ASTRIDE + col] = h.v;
        }
    }
    __syncthreads();

    // ---- K-loop: 6 steps of 32; 4 m-tiles x 2 n-tiles per wave (swapped) ----
    floatx4 acc[4][2];
#pragma unroll
    for (int m = 0; m < 4; ++m)
#pragma unroll
        for (int n = 0; n < 2; ++n) acc[m][n] = (floatx4){0.f, 0.f, 0.f, 0.f};

#pragma unroll
    for (int s = 0; s < 6; ++s) {
#pragma unroll
        for (int m = 0; m < 4; ++m) {
            short8 af = *(const short8*)&a_lds[(m * 16 + nl + (s >> 1)) * ASTRIDE
                                               + (s & 1) * 32 + q * 8];
#pragma unroll
            for (int n = 0; n < 2; ++n)
                acc[m][n] = __builtin_amdgcn_mfma_f32_16x16x32_bf16(
                    bfrag[s][n], af, acc[m][n], 0, 0, 0);
        }
    }

    // ---- epilogue: lane(nl,q) holds f = base+q*4+r (r=0..3), l = l0+m*16+nl
    //      -> one float4 store per (m,n) ----
#pragma unroll
    for (int n = 0; n < 2; ++n) {
        const int fb = (wave * 2 + n) * 16 + q * 4;
#pragma unroll
        for (int m = 0; m < 4; ++m) {
            const int l = l0 + m * 16 + nl;
            if (l < L_OUT) {
                float4 v;
                v.x = acc[m][n][0] + bv[n].x;
                v.y = acc[m][n][1] + bv[n].y;
                v.z = acc[m][n][2] + bv[n].z;
                v.w = acc[m][n][3] + bv[n].w;
                v.x = v.x > 0.f ? v.x : 0.f;
                v.y = v.y > 0.f ? v.y : 0.f;
                v.z = v.z > 0.f ? v.z : 0.f;
                v.w = v.w > 0.f ? v.w : 0.f;
                *(float4*)(out + ((size_t)b * L_OUT + l) * F_OUT + fb) = v;
            }
        }
    }
}

extern "C" void kernel_launch(void* const* d_in, const int* in_sizes, int n_in,
                              void* d_out, int out_size, void* d_ws, size_t ws_size,
                              hipStream_t stream) {
    const float* x    = (const float*)d_in[0];
    const float* w    = (const float*)d_in[1];
    const float* bias = (const float*)d_in[2];
    float* out        = (float*)d_out;

    if (d_ws != nullptr && ws_size >= (size_t)WTAB_ELEMS * sizeof(short8)) {
        short8* wtab = (short8*)d_ws;
        w_prep<<<dim3((WTAB_ELEMS + 255) / 256), 256, 0, stream>>>(w, wtab);
        conv1d_mfma<true><<<dim3(NGRID), 256, 0, stream>>>(x, w, bias, out, wtab);
    } else {
        conv1d_mfma<false><<<dim3(NGRID), 256, 0, stream>>>(x, w, bias, out, nullptr);
    }
}